// Round 3
// baseline (248.941 us; speedup 1.0000x reference)
//
#include <hip/hip_runtime.h>
#include <hip/hip_bf16.h>
#include <stdint.h>

#define Bb 8
#define Tt 256
#define TCC 768
#define TKV 1024
#define NS 1024
#define NH 16
#define DH 64
#define QK_SCALE 0.125f

typedef short bf16x8 __attribute__((ext_vector_type(8)));
typedef float f32x4 __attribute__((ext_vector_type(4)));
typedef unsigned int u32;

__device__ __forceinline__ unsigned short f2bf(float f) {
  union { float f; uint32_t u; } v; v.f = f;
  uint32_t u = v.u;
  u += 0x7fff + ((u >> 16) & 1);   // round-to-nearest-even
  return (unsigned short)(u >> 16);
}

// async global->LDS, 16B per lane (dest = wave-uniform base + lane*16)
__device__ __forceinline__ void gload16(const unsigned short* g, unsigned short* l) {
  __builtin_amdgcn_global_load_lds(
      (__attribute__((address_space(1))) u32*)g,
      (__attribute__((address_space(3))) u32*)l,
      16, 0, 0);
}

// ---------------- kernel 1: x -> bf16, cache_k -> bf16 (into concat slot) ----
__global__ __launch_bounds__(256) void convert_flat(
    const float* __restrict__ x, const float* __restrict__ ck,
    unsigned short* __restrict__ xb, unsigned short* __restrict__ kb) {
  const int64_t nx4 = (int64_t)Bb * Tt * NS / 4;        // 524288
  const int64_t nk4 = (int64_t)Bb * TCC * NS / 4;       // 1572864
  int64_t stride = (int64_t)gridDim.x * blockDim.x;
  for (int64_t t = (int64_t)blockIdx.x * blockDim.x + threadIdx.x; t < nx4 + nk4; t += stride) {
    if (t < nx4) {
      float4 v = ((const float4*)x)[t];
      ushort4 o; o.x = f2bf(v.x); o.y = f2bf(v.y); o.z = f2bf(v.z); o.w = f2bf(v.w);
      ((ushort4*)xb)[t] = o;
    } else {
      int64_t e = t - nx4;
      float4 v = ((const float4*)ck)[e];
      ushort4 o; o.x = f2bf(v.x); o.y = f2bf(v.y); o.z = f2bf(v.z); o.w = f2bf(v.w);
      int64_t el = e * 4;
      int64_t b = el / ((int64_t)TCC * NS);
      int64_t rem = el % ((int64_t)TCC * NS);
      int64_t d = b * (int64_t)TKV * NS + rem;          // rows 0..767 of concat K
      ((ushort4*)kb)[d / 4] = o;
    }
  }
}

// ------- kernel 2: W -> bf16 transposed [N][K]; cache_v -> bf16 [b][h][d][t] -
__global__ __launch_bounds__(256) void transpose_convert(
    const float* __restrict__ Wq, const float* __restrict__ Wk,
    const float* __restrict__ Wv, const float* __restrict__ Wo,
    const float* __restrict__ cv,
    unsigned short* __restrict__ wqt, unsigned short* __restrict__ wkt,
    unsigned short* __restrict__ wvt, unsigned short* __restrict__ wot,
    unsigned short* __restrict__ vbt) {
  __shared__ float tile[64][65];
  int bid = blockIdx.x;
  const float* src; unsigned short* dst;
  if (bid < 1024) {                       // 4 weight mats, 16x16 tiles of 64x64
    int mat = bid >> 8, t = bid & 255;
    int tr = t >> 4, tc = t & 15;
    const float* W = (mat == 0) ? Wq : (mat == 1) ? Wk : (mat == 2) ? Wv : Wo;
    unsigned short* Wt = (mat == 0) ? wqt : (mat == 1) ? wkt : (mat == 2) ? wvt : wot;
    src = W + (int64_t)(tr * 64) * 1024 + tc * 64;
    dst = Wt + (int64_t)(tc * 64) * 1024 + tr * 64;
  } else {                                // cache_v: per b, [768][1024] -> [1024][1024] cols 0..767
    int e = bid - 1024;                   // 8 * 12 * 16 = 1536 tiles
    int b = e / 192; int t = e % 192;
    int st = t >> 4, ct = t & 15;
    src = cv + (int64_t)b * TCC * NS + (int64_t)(st * 64) * 1024 + ct * 64;
    dst = vbt + (int64_t)b * NS * TKV + (int64_t)(ct * 64) * 1024 + st * 64;
  }
  for (int e = threadIdx.x; e < 1024; e += 256) {        // float4 reads
    int i = e >> 4, j4 = (e & 15) * 4;
    float4 v = *(const float4*)&src[(int64_t)i * 1024 + j4];
    tile[i][j4] = v.x; tile[i][j4 + 1] = v.y; tile[i][j4 + 2] = v.z; tile[i][j4 + 3] = v.w;
  }
  __syncthreads();
  for (int e = threadIdx.x; e < 1024; e += 256) {        // ushort4 writes
    int i = e >> 4, j4 = (e & 15) * 4;
    ushort4 o;
    o.x = f2bf(tile[j4][i]); o.y = f2bf(tile[j4 + 1][i]);
    o.z = f2bf(tile[j4 + 2][i]); o.w = f2bf(tile[j4 + 3][i]);
    *(ushort4*)&dst[(int64_t)i * 1024 + j4] = o;
  }
}

// -------- kernel 3/5: bf16 MFMA GEMM, m97 structure (global_load_lds) --------
// MODE 0: BM=128, grid 384 (QKV).  MODE 1: BM=64, grid 256 (out proj).
// A: [M][1024] bf16 row-major.  Bt: [N][1024] bf16 (W^T).  LDS linear [BM][32].
template <int MODE>
__global__ __launch_bounds__(256) void gemm_mfma(
    const unsigned short* __restrict__ A,
    const unsigned short* __restrict__ Bt0, const unsigned short* __restrict__ Bt1,
    const unsigned short* __restrict__ Bt2,
    const float* __restrict__ bq, const float* __restrict__ bv,
    const float* __restrict__ bo,
    unsigned short* __restrict__ qb,
    float* __restrict__ okf, float* __restrict__ ovf,
    unsigned short* __restrict__ kb, unsigned short* __restrict__ vbt,
    float* __restrict__ outf) {
  constexpr int BM = (MODE == 0) ? 128 : 64;
  constexpr int NT = (MODE == 0) ? 4 : 2;
  __shared__ __align__(16) unsigned short As[BM * 32];
  __shared__ __align__(16) unsigned short Bs[128 * 32];
  int tid = threadIdx.x, lane = tid & 63, w = tid >> 6;
  int lr = lane & 15, hi = lane >> 4;
  int wr = (MODE == 0) ? (w >> 1) : 0;
  int colw = (MODE == 0) ? ((w & 1) * 64) : (w * 32);

  int tm, tn, seg, col0;
  const unsigned short* Bt;
  if (MODE == 0) {
    tm = blockIdx.x & 15; tn = blockIdx.x >> 4;            // tn 0..23
    seg = tn >> 3; col0 = (tn & 7) * 128;
    Bt = (seg == 0) ? Bt0 : (seg == 1) ? Bt1 : Bt2;
  } else {
    tm = blockIdx.x & 31; tn = blockIdx.x >> 5;            // tn 0..7
    seg = 0; col0 = tn * 128;
    Bt = Bt0;
  }
  int m0 = tm * BM;

  f32x4 acc[4][NT];
#pragma unroll
  for (int i = 0; i < 4; i++)
#pragma unroll
    for (int j = 0; j < NT; j++) acc[i][j] = (f32x4){0.f, 0.f, 0.f, 0.f};

  for (int k0 = 0; k0 < 1024; k0 += 32) {
#pragma unroll
    for (int i = 0; i < BM / 64; i++) {                    // A staging
      int slot = i * 256 + tid;
      int r = slot >> 2, c = (slot & 3) * 8;
      gload16(&A[(int64_t)(m0 + r) * 1024 + k0 + c], &As[slot * 8]);
    }
#pragma unroll
    for (int i = 0; i < 2; i++) {                          // B staging (128 rows)
      int slot = i * 256 + tid;
      int r = slot >> 2, c = (slot & 3) * 8;
      gload16(&Bt[(int64_t)(col0 + r) * 1024 + k0 + c], &Bs[slot * 8]);
    }
    __syncthreads();                                       // drains vmcnt
    bf16x8 af[4], bfr[NT];
#pragma unroll
    for (int mt = 0; mt < 4; mt++)
      af[mt] = *(const bf16x8*)&As[(wr * 64 + mt * 16 + lr) * 32 + hi * 8];
#pragma unroll
    for (int nt = 0; nt < NT; nt++)
      bfr[nt] = *(const bf16x8*)&Bs[(colw + nt * 16 + lr) * 32 + hi * 8];
#pragma unroll
    for (int mt = 0; mt < 4; mt++)
#pragma unroll
      for (int nt = 0; nt < NT; nt++)
        acc[mt][nt] = __builtin_amdgcn_mfma_f32_16x16x32_bf16(af[mt], bfr[nt], acc[mt][nt], 0, 0, 0);
    __syncthreads();
  }

  // epilogue: D[row=(l>>4)*4+r][col=l&15] per 16x16 tile
#pragma unroll
  for (int mt = 0; mt < 4; mt++)
#pragma unroll
    for (int nt = 0; nt < NT; nt++) {
      int row = m0 + wr * 64 + mt * 16 + hi * 4;
      int col = col0 + colw + nt * 16 + lr;                // segment-local 0..1023
      if (MODE == 1) {
        float bias = bo[col];
#pragma unroll
        for (int r = 0; r < 4; r++)
          outf[(int64_t)(row + r) * 1024 + col] = acc[mt][nt][r] + bias;
      } else if (seg == 0) {                               // q: (acc+bq)*scale -> bf16
        float bias = bq[col];
#pragma unroll
        for (int r = 0; r < 4; r++)
          qb[(int64_t)(row + r) * 1024 + col] = f2bf((acc[mt][nt][r] + bias) * QK_SCALE);
      } else if (seg == 1) {                               // new_k: fp32 out + bf16 concat
#pragma unroll
        for (int r = 0; r < 4; r++) {
          float v = acc[mt][nt][r];
          okf[(int64_t)(row + r) * 1024 + col] = v;
          int b = (row + r) >> 8, t = (row + r) & 255;
          kb[((int64_t)(b * TKV + TCC + t)) * 1024 + col] = f2bf(v);
        }
      } else {                                             // new_v: fp32 out + bf16 transposed
        float bias = bv[col];
        int b = row >> 8, t0 = row & 255;
        int64_t voff = ((int64_t)(b * NH + (col >> 6)) * DH + (col & 63)) * TKV + TCC + t0;
        float v0 = acc[mt][nt][0] + bias, v1 = acc[mt][nt][1] + bias,
              v2 = acc[mt][nt][2] + bias, v3 = acc[mt][nt][3] + bias;
        ovf[(int64_t)(row + 0) * 1024 + col] = v0;
        ovf[(int64_t)(row + 1) * 1024 + col] = v1;
        ovf[(int64_t)(row + 2) * 1024 + col] = v2;
        ovf[(int64_t)(row + 3) * 1024 + col] = v3;
        ushort4 pk; pk.x = f2bf(v0); pk.y = f2bf(v1); pk.z = f2bf(v2); pk.w = f2bf(v3);
        *(ushort4*)&vbt[voff] = pk;
      }
    }
}

// ---------------- kernel 4: flash attention, no K/V staging ------------------
// grid 2048 = B*H*16 qblocks of 16 rows; 4 waves split KV (256 each), merge at end.
// K/V fragments load straight from L2; P transpose via wave-private LDS (no barrier).
__global__ __launch_bounds__(256) void attn(
    const unsigned short* __restrict__ qb, const unsigned short* __restrict__ kb,
    const unsigned short* __restrict__ vbt, const float* __restrict__ mask,
    unsigned short* __restrict__ wvb) {
  __shared__ __align__(16) float OshF[4 * 16 * 64];        // 16 KB, aliased by Ps
  __shared__ float Msh[4][16];
  __shared__ float Lsh[4][16];
  unsigned short* Ps = (unsigned short*)OshF;              // [4][16][76] bf16 = 9728 B

  int tid = threadIdx.x, lane = tid & 63, w = tid >> 6;
  int lr = lane & 15, hi = lane >> 4;
  int bid = blockIdx.x;
  int logical = (bid & 7) * 256 + (bid >> 3);              // XCD swizzle (2048 % 8 == 0)
  int qt = logical & 15, bh = logical >> 4, b = bh >> 4, h = bh & 15;
  int q0 = qt * 16;

  const unsigned short* qp = qb + ((int64_t)(b * Tt + q0 + lr)) * 1024 + h * DH + hi * 8;
  bf16x8 aq0 = *(const bf16x8*)qp;
  bf16x8 aq1 = *(const bf16x8*)(qp + 32);

  f32x4 o[4];
#pragma unroll
  for (int nt = 0; nt < 4; nt++) o[nt] = (f32x4){0.f, 0.f, 0.f, 0.f};
  float m[4] = {-1e30f, -1e30f, -1e30f, -1e30f};
  float l[4] = {0.f, 0.f, 0.f, 0.f};

  const unsigned short* kbase = kb + (int64_t)b * TKV * 1024 + h * DH;
  const unsigned short* vbase = vbt + (int64_t)bh * DH * TKV;
  const float* mbase = mask + (int64_t)(q0 + hi * 4) * TKV;

  for (int ci = 0; ci < 4; ci++) {
    int kv0 = (w * 4 + ci) * 64;                           // wave w owns kv [w*256, w*256+256)
    bf16x8 bk0[4], bk1[4], bv0[4], bv1[4];
#pragma unroll
    for (int nt = 0; nt < 4; nt++) {
      const unsigned short* kr = &kbase[(int64_t)(kv0 + nt * 16 + lr) * 1024 + hi * 8];
      bk0[nt] = *(const bf16x8*)kr;
      bk1[nt] = *(const bf16x8*)(kr + 32);
      const unsigned short* vr = &vbase[(int64_t)(nt * 16 + lr) * TKV + kv0 + hi * 8];
      bv0[nt] = *(const bf16x8*)vr;
      bv1[nt] = *(const bf16x8*)(vr + 32);
    }

    f32x4 s[4];
    __builtin_amdgcn_s_setprio(1);
#pragma unroll
    for (int nt = 0; nt < 4; nt++) {
      f32x4 z = (f32x4){0.f, 0.f, 0.f, 0.f};
      z = __builtin_amdgcn_mfma_f32_16x16x32_bf16(aq0, bk0[nt], z, 0, 0, 0);
      z = __builtin_amdgcn_mfma_f32_16x16x32_bf16(aq1, bk1[nt], z, 0, 0, 0);
      s[nt] = z;
    }
    __builtin_amdgcn_s_setprio(0);

#pragma unroll
    for (int nt = 0; nt < 4; nt++)
#pragma unroll
      for (int r = 0; r < 4; r++)
        s[nt][r] += mbase[(int64_t)r * TKV + kv0 + nt * 16 + lr];

    // online softmax (rows hi*4+r live in 16-lane lr-groups)
    float cm[4];
#pragma unroll
    for (int r = 0; r < 4; r++) {
      cm[r] = fmaxf(fmaxf(s[0][r], s[1][r]), fmaxf(s[2][r], s[3][r]));
#pragma unroll
      for (int d = 1; d < 16; d <<= 1) cm[r] = fmaxf(cm[r], __shfl_xor(cm[r], d));
    }
    float al[4], rs[4];
#pragma unroll
    for (int r = 0; r < 4; r++) {
      float nm = fmaxf(m[r], cm[r]);
      al[r] = __expf(m[r] - nm);
      m[r] = nm;
      rs[r] = 0.f;
    }
#pragma unroll
    for (int nt = 0; nt < 4; nt++)
#pragma unroll
      for (int r = 0; r < 4; r++) {
        s[nt][r] = __expf(s[nt][r] - m[r]);
        rs[r] += s[nt][r];
      }
#pragma unroll
    for (int r = 0; r < 4; r++) {
#pragma unroll
      for (int d = 1; d < 16; d <<= 1) rs[r] += __shfl_xor(rs[r], d);
      l[r] = l[r] * al[r] + rs[r];
    }
#pragma unroll
    for (int nt = 0; nt < 4; nt++)
#pragma unroll
      for (int r = 0; r < 4; r++) o[nt][r] *= al[r];

    // P -> bf16 via wave-private LDS (pad 76 -> conflict-free writes, no barrier)
#pragma unroll
    for (int nt = 0; nt < 4; nt++)
#pragma unroll
      for (int r = 0; r < 4; r++)
        Ps[w * 1216 + (hi * 4 + r) * 76 + nt * 16 + lr] = f2bf(s[nt][r]);
    bf16x8 pa0 = *(const bf16x8*)&Ps[w * 1216 + lr * 76 + hi * 8];
    bf16x8 pa1 = *(const bf16x8*)&Ps[w * 1216 + lr * 76 + 32 + hi * 8];

    __builtin_amdgcn_s_setprio(1);
#pragma unroll
    for (int nt = 0; nt < 4; nt++) {
      o[nt] = __builtin_amdgcn_mfma_f32_16x16x32_bf16(pa0, bv0[nt], o[nt], 0, 0, 0);
      o[nt] = __builtin_amdgcn_mfma_f32_16x16x32_bf16(pa1, bv1[nt], o[nt], 0, 0, 0);
    }
    __builtin_amdgcn_s_setprio(0);
  }

  // ----- merge the 4 per-wave partials -----
  if (lr == 0) {
#pragma unroll
    for (int r = 0; r < 4; r++) { Msh[w][hi * 4 + r] = m[r]; Lsh[w][hi * 4 + r] = l[r]; }
  }
  __syncthreads();                                          // Ps dead after this point
  float fw[4];
#pragma unroll
  for (int r = 0; r < 4; r++) {
    int row = hi * 4 + r;
    float M = fmaxf(fmaxf(Msh[0][row], Msh[1][row]), fmaxf(Msh[2][row], Msh[3][row]));
    fw[r] = __expf(m[r] - M);
  }
  float* Osh = OshF + w * 1024;
#pragma unroll
  for (int nt = 0; nt < 4; nt++)
#pragma unroll
    for (int r = 0; r < 4; r++)
      Osh[(hi * 4 + r) * 64 + nt * 16 + lr] = o[nt][r] * fw[r];
  __syncthreads();
  {
    int row = tid >> 4, d0 = (tid & 15) * 4;
    float M = fmaxf(fmaxf(Msh[0][row], Msh[1][row]), fmaxf(Msh[2][row], Msh[3][row]));
    float lsum = Lsh[0][row] * __expf(Msh[0][row] - M) + Lsh[1][row] * __expf(Msh[1][row] - M) +
                 Lsh[2][row] * __expf(Msh[2][row] - M) + Lsh[3][row] * __expf(Msh[3][row] - M);
    float inv = 1.f / lsum;
    float v[4];
#pragma unroll
    for (int t = 0; t < 4; t++) {
      int idx = row * 64 + d0 + t;
      v[t] = (OshF[idx] + OshF[1024 + idx] + OshF[2048 + idx] + OshF[3072 + idx]) * inv;
    }
    ushort4 pk; pk.x = f2bf(v[0]); pk.y = f2bf(v[1]); pk.z = f2bf(v[2]); pk.w = f2bf(v[3]);
    *(ushort4*)&wvb[(int64_t)(b * Tt + q0 + row) * 1024 + h * DH + d0] = pk;
  }
}

// ---------------------------------------------------------------------------
extern "C" void kernel_launch(void* const* d_in, const int* in_sizes, int n_in,
                              void* d_out, int out_size, void* d_ws, size_t ws_size,
                              hipStream_t stream) {
  const float* x    = (const float*)d_in[0];
  const float* mask = (const float*)d_in[1];
  const float* ck   = (const float*)d_in[2];
  const float* cv   = (const float*)d_in[3];
  const float* Wq   = (const float*)d_in[4];
  const float* bq   = (const float*)d_in[5];
  const float* Wk   = (const float*)d_in[6];
  const float* Wv   = (const float*)d_in[7];
  const float* bv   = (const float*)d_in[8];
  const float* Wo   = (const float*)d_in[9];
  const float* bo   = (const float*)d_in[10];

  const int64_t NT = (int64_t)Bb * Tt * NS;   // 2097152
  float* outp = (float*)d_out;
  float* okf  = outp + NT;
  float* ovf  = outp + 2 * NT;

  char* ws = (char*)d_ws;
  unsigned short* xb  = (unsigned short*)(ws);                       // 4 MB
  unsigned short* wqt = (unsigned short*)(ws + (4LL << 20));         // 2 MB each
  unsigned short* wkt = (unsigned short*)(ws + (6LL << 20));
  unsigned short* wvt = (unsigned short*)(ws + (8LL << 20));
  unsigned short* wot = (unsigned short*)(ws + (10LL << 20));
  unsigned short* qbw = (unsigned short*)(ws + (12LL << 20));        // 4 MB
  unsigned short* kbw = (unsigned short*)(ws + (16LL << 20));        // 16 MB
  unsigned short* vbt = (unsigned short*)(ws + (32LL << 20));        // 16 MB
  unsigned short* wvb = (unsigned short*)(ws + (48LL << 20));        // 4 MB

  convert_flat<<<2048, 256, 0, stream>>>(x, ck, xb, kbw);
  transpose_convert<<<2560, 256, 0, stream>>>(Wq, Wk, Wv, Wo, cv, wqt, wkt, wvt, wot, vbt);
  gemm_mfma<0><<<384, 256, 0, stream>>>(xb, wqt, wkt, wvt, bq, bv, bo,
                                        qbw, okf, ovf, kbw, vbt, outp);
  attn<<<2048, 256, 0, stream>>>(qbw, kbw, vbt, mask, wvb);
  gemm_mfma<1><<<256, 256, 0, stream>>>(wvb, wot, wot, wot, bq, bv, bo,
                                        qbw, okf, ovf, kbw, vbt, outp);
}

// Round 4
// 211.502 us; speedup vs baseline: 1.1770x; 1.1770x over previous
//
#include <hip/hip_runtime.h>
#include <hip/hip_bf16.h>
#include <stdint.h>

#define Bb 8
#define Tt 256
#define TCC 768
#define TKV 1024
#define NS 1024
#define NH 16
#define DH 64
#define QK_SCALE 0.125f

typedef short bf16x8 __attribute__((ext_vector_type(8)));
typedef float f32x4 __attribute__((ext_vector_type(4)));
typedef unsigned int u32;

__device__ __forceinline__ unsigned short f2bf(float f) {
  union { float f; uint32_t u; } v; v.f = f;
  uint32_t u = v.u;
  u += 0x7fff + ((u >> 16) & 1);   // round-to-nearest-even
  return (unsigned short)(u >> 16);
}

// async global->LDS, 16B per lane (dest = wave-uniform base + lane*16)
__device__ __forceinline__ void gload16(const unsigned short* g, unsigned short* l) {
  __builtin_amdgcn_global_load_lds(
      (__attribute__((address_space(1))) u32*)g,
      (__attribute__((address_space(3))) u32*)l,
      16, 0, 0);
}

// ---------------- kernel 1: x -> bf16, cache_k -> bf16 (into concat slot) ----
__global__ __launch_bounds__(256) void convert_flat(
    const float* __restrict__ x, const float* __restrict__ ck,
    unsigned short* __restrict__ xb, unsigned short* __restrict__ kb) {
  const int64_t nx4 = (int64_t)Bb * Tt * NS / 4;        // 524288
  const int64_t nk4 = (int64_t)Bb * TCC * NS / 4;       // 1572864
  int64_t stride = (int64_t)gridDim.x * blockDim.x;
  for (int64_t t = (int64_t)blockIdx.x * blockDim.x + threadIdx.x; t < nx4 + nk4; t += stride) {
    if (t < nx4) {
      float4 v = ((const float4*)x)[t];
      ushort4 o; o.x = f2bf(v.x); o.y = f2bf(v.y); o.z = f2bf(v.z); o.w = f2bf(v.w);
      ((ushort4*)xb)[t] = o;
    } else {
      int64_t e = t - nx4;
      float4 v = ((const float4*)ck)[e];
      ushort4 o; o.x = f2bf(v.x); o.y = f2bf(v.y); o.z = f2bf(v.z); o.w = f2bf(v.w);
      int64_t el = e * 4;
      int64_t b = el / ((int64_t)TCC * NS);
      int64_t rem = el % ((int64_t)TCC * NS);
      int64_t d = b * (int64_t)TKV * NS + rem;          // rows 0..767 of concat K
      ((ushort4*)kb)[d / 4] = o;
    }
  }
}

// ------- kernel 2: W -> bf16 transposed [N][K]; cache_v -> bf16 [b][h][d][t] -
__global__ __launch_bounds__(256) void transpose_convert(
    const float* __restrict__ Wq, const float* __restrict__ Wk,
    const float* __restrict__ Wv, const float* __restrict__ Wo,
    const float* __restrict__ cv,
    unsigned short* __restrict__ wqt, unsigned short* __restrict__ wkt,
    unsigned short* __restrict__ wvt, unsigned short* __restrict__ wot,
    unsigned short* __restrict__ vbt) {
  __shared__ float tile[64][65];
  int bid = blockIdx.x;
  const float* src; unsigned short* dst;
  if (bid < 1024) {                       // 4 weight mats, 16x16 tiles of 64x64
    int mat = bid >> 8, t = bid & 255;
    int tr = t >> 4, tc = t & 15;
    const float* W = (mat == 0) ? Wq : (mat == 1) ? Wk : (mat == 2) ? Wv : Wo;
    unsigned short* Wt = (mat == 0) ? wqt : (mat == 1) ? wkt : (mat == 2) ? wvt : wot;
    src = W + (int64_t)(tr * 64) * 1024 + tc * 64;
    dst = Wt + (int64_t)(tc * 64) * 1024 + tr * 64;
  } else {                                // cache_v: per b, [768][1024] -> [1024][1024] cols 0..767
    int e = bid - 1024;                   // 8 * 12 * 16 = 1536 tiles
    int b = e / 192; int t = e % 192;
    int st = t >> 4, ct = t & 15;
    src = cv + (int64_t)b * TCC * NS + (int64_t)(st * 64) * 1024 + ct * 64;
    dst = vbt + (int64_t)b * NS * TKV + (int64_t)(ct * 64) * 1024 + st * 64;
  }
  for (int e = threadIdx.x; e < 1024; e += 256) {        // float4 reads
    int i = e >> 4, j4 = (e & 15) * 4;
    float4 v = *(const float4*)&src[(int64_t)i * 1024 + j4];
    tile[i][j4] = v.x; tile[i][j4 + 1] = v.y; tile[i][j4 + 2] = v.z; tile[i][j4 + 3] = v.w;
  }
  __syncthreads();
  for (int e = threadIdx.x; e < 1024; e += 256) {        // ushort4 writes
    int i = e >> 4, j4 = (e & 15) * 4;
    ushort4 o;
    o.x = f2bf(tile[j4][i]); o.y = f2bf(tile[j4 + 1][i]);
    o.z = f2bf(tile[j4 + 2][i]); o.w = f2bf(tile[j4 + 3][i]);
    *(ushort4*)&dst[(int64_t)i * 1024 + j4] = o;
  }
}

// -------- kernel 3/5: bf16 MFMA GEMM, 2-phase dbuf, BK=64, XOR-swizzled LDS --
// MODE 0: BM=64 BN=128, grid 768 (QKV).  MODE 1: BM=64 BN=64, grid 512 (Wo).
// A: [M][1024] bf16 row-major.  Bt: [N][1024] bf16 (W^T).
// LDS linear (gload_lds), swizzle: chunk_lds = chunk_g ^ (row&7) via pre-swizzled
// global source; reads apply the same XOR -> at the b128 8-phase bank floor.
template <int MODE>
__global__ __launch_bounds__(256) void gemm_mfma(
    const unsigned short* __restrict__ A,
    const unsigned short* __restrict__ Bt0, const unsigned short* __restrict__ Bt1,
    const unsigned short* __restrict__ Bt2,
    const float* __restrict__ bq, const float* __restrict__ bv,
    const float* __restrict__ bo,
    unsigned short* __restrict__ qb,
    float* __restrict__ okf, float* __restrict__ ovf,
    unsigned short* __restrict__ kb, unsigned short* __restrict__ vbt,
    float* __restrict__ outf) {
  constexpr int BM = 64;
  constexpr int BN = (MODE == 0) ? 128 : 64;
  constexpr int MT = 2;                  // per-wave 16-row fragments
  constexpr int NTf = BN / 32;           // per-wave 16-col fragments (4 or 2)
  __shared__ __align__(16) unsigned short As[2][BM * 64];
  __shared__ __align__(16) unsigned short Bs[2][BN * 64];

  int tid = threadIdx.x, lane = tid & 63, w = tid >> 6;
  int lr = lane & 15, hi = lane >> 4;
  int wm = w >> 1, wn = w & 1;           // 2x2 wave grid

  int bid = blockIdx.x;
  int cpx = gridDim.x >> 3;
  int logical = (bid & 7) * cpx + (bid >> 3);   // XCD swizzle (grid % 8 == 0)

  int tm = logical & 31;                 // 32 M tiles of 64
  int tn = logical >> 5;
  int seg, col0;
  const unsigned short* Bt;
  if (MODE == 0) {
    seg = tn >> 3; col0 = (tn & 7) * 128;
    Bt = (seg == 0) ? Bt0 : (seg == 1) ? Bt1 : Bt2;
  } else {
    seg = 0; col0 = tn * 64;
    Bt = Bt0;
  }
  int m0 = tm * 64;

  int srow = lane >> 3;                  // row within 8-row staging group
  int sch8 = (((lane & 7) ^ srow)) * 8;  // swizzled source chunk (ushorts)
  int sw = lr & 7;                       // read-side swizzle key

  f32x4 acc[MT][NTf];
#pragma unroll
  for (int i = 0; i < MT; i++)
#pragma unroll
    for (int j = 0; j < NTf; j++) acc[i][j] = (f32x4){0.f, 0.f, 0.f, 0.f};

  auto STAGE = [&](int buf, int k0) {
#pragma unroll
    for (int i = 0; i < 2; i++) {        // A: BM=64 rows, 2 instr/wave
      int rb = w * 16 + i * 8;
      gload16(&A[(int64_t)(m0 + rb + srow) * 1024 + k0 + sch8], &As[buf][rb * 64]);
    }
#pragma unroll
    for (int i = 0; i < BN / 32; i++) {  // B: BN rows
      int rb = w * (BN / 4) + i * 8;
      gload16(&Bt[(int64_t)(col0 + rb + srow) * 1024 + k0 + sch8], &Bs[buf][rb * 64]);
    }
  };

  STAGE(0, 0);
  __syncthreads();
  int cur = 0;
  for (int step = 0; step < 16; ++step) {
    if (step < 15) STAGE(cur ^ 1, (step + 1) * 64);
    bf16x8 af[2][MT], bfr[2][NTf];
#pragma unroll
    for (int kk = 0; kk < 2; kk++) {
      int ch = ((kk * 4 + hi) ^ sw) * 8;
#pragma unroll
      for (int mt = 0; mt < MT; mt++)
        af[kk][mt] = *(const bf16x8*)&As[cur][(wm * 32 + mt * 16 + lr) * 64 + ch];
#pragma unroll
      for (int nt = 0; nt < NTf; nt++)
        bfr[kk][nt] = *(const bf16x8*)&Bs[cur][(wn * (BN / 2) + nt * 16 + lr) * 64 + ch];
    }
#pragma unroll
    for (int kk = 0; kk < 2; kk++)
#pragma unroll
      for (int mt = 0; mt < MT; mt++)
#pragma unroll
        for (int nt = 0; nt < NTf; nt++)
          acc[mt][nt] = __builtin_amdgcn_mfma_f32_16x16x32_bf16(af[kk][mt], bfr[kk][nt],
                                                               acc[mt][nt], 0, 0, 0);
    __syncthreads();
    cur ^= 1;
  }

  // epilogue: D[row=(l>>4)*4+r][col=l&15] per 16x16 tile
#pragma unroll
  for (int mt = 0; mt < MT; mt++)
#pragma unroll
    for (int nt = 0; nt < NTf; nt++) {
      int row = m0 + wm * 32 + mt * 16 + hi * 4;
      int col = col0 + wn * (BN / 2) + nt * 16 + lr;     // segment-local 0..1023
      if (MODE == 1) {
        float bias = bo[col];
#pragma unroll
        for (int r = 0; r < 4; r++)
          outf[(int64_t)(row + r) * 1024 + col] = acc[mt][nt][r] + bias;
      } else if (seg == 0) {                             // q: (acc+bq)*scale -> bf16
        float bias = bq[col];
#pragma unroll
        for (int r = 0; r < 4; r++)
          qb[(int64_t)(row + r) * 1024 + col] = f2bf((acc[mt][nt][r] + bias) * QK_SCALE);
      } else if (seg == 1) {                             // new_k: fp32 out + bf16 concat
#pragma unroll
        for (int r = 0; r < 4; r++) {
          float v = acc[mt][nt][r];
          okf[(int64_t)(row + r) * 1024 + col] = v;
          int b = (row + r) >> 8, t = (row + r) & 255;
          kb[((int64_t)(b * TKV + TCC + t)) * 1024 + col] = f2bf(v);
        }
      } else {                                           // new_v: fp32 out + bf16 transposed
        float bias = bv[col];
        int b = row >> 8, t0 = row & 255;
        int64_t voff = ((int64_t)(b * NH + (col >> 6)) * DH + (col & 63)) * TKV + TCC + t0;
        float v0 = acc[mt][nt][0] + bias, v1 = acc[mt][nt][1] + bias,
              v2 = acc[mt][nt][2] + bias, v3 = acc[mt][nt][3] + bias;
        ovf[(int64_t)(row + 0) * 1024 + col] = v0;
        ovf[(int64_t)(row + 1) * 1024 + col] = v1;
        ovf[(int64_t)(row + 2) * 1024 + col] = v2;
        ovf[(int64_t)(row + 3) * 1024 + col] = v3;
        ushort4 pk; pk.x = f2bf(v0); pk.y = f2bf(v1); pk.z = f2bf(v2); pk.w = f2bf(v3);
        *(ushort4*)&vbt[voff] = pk;
      }
    }
}

// ------- kernel 4: flash attention, LDS-staged K/V, 2-phase dbuf -------------
// grid 512 = B*H*4 qblocks of 64 rows; 4 waves own disjoint 16-row groups, each
// processes the FULL 1024 KV (no merge). K/V chunk (64) staged via gload16 with
// XOR-swizzled source; one barrier per chunk (T3 2-phase).
__global__ __launch_bounds__(256) void attn(
    const unsigned short* __restrict__ qb, const unsigned short* __restrict__ kb,
    const unsigned short* __restrict__ vbt, const float* __restrict__ mask,
    unsigned short* __restrict__ wvb) {
  __shared__ __align__(16) unsigned short Ks[2][64 * 64];   // [kv][d] swizzled
  __shared__ __align__(16) unsigned short Vs[2][64 * 64];   // [d][kv] swizzled
  __shared__ unsigned short Ps[4][16 * 76];                 // wave-private P, pad 76

  int tid = threadIdx.x, lane = tid & 63, w = tid >> 6;
  int lr = lane & 15, hi = lane >> 4;
  int bid = blockIdx.x;
  int logical = (bid & 7) * 64 + (bid >> 3);                // XCD swizzle (512%8==0)
  int qt = logical & 3, bh = logical >> 2, b = bh >> 4, h = bh & 15;
  int q0 = qt * 64 + w * 16;                                // this wave's q rows

  const unsigned short* qp = qb + ((int64_t)(b * Tt + q0 + lr)) * 1024 + h * DH + hi * 8;
  bf16x8 aq0 = *(const bf16x8*)qp;
  bf16x8 aq1 = *(const bf16x8*)(qp + 32);

  f32x4 o[4];
#pragma unroll
  for (int nt = 0; nt < 4; nt++) o[nt] = (f32x4){0.f, 0.f, 0.f, 0.f};
  float m[4] = {-1e30f, -1e30f, -1e30f, -1e30f};
  float l[4] = {0.f, 0.f, 0.f, 0.f};

  const unsigned short* kbase = kb + (int64_t)b * TKV * 1024 + h * DH;
  const unsigned short* vbase = vbt + (int64_t)bh * DH * TKV;
  const float* mbase = mask + (int64_t)(q0 + hi * 4) * TKV;

  int srow = lane >> 3;
  int sch8 = ((lane & 7) ^ srow) * 8;
  int sw = lr & 7;

  auto STAGE = [&](int buf, int kv0) {
#pragma unroll
    for (int i = 0; i < 2; i++) {
      int rb = w * 16 + i * 8;
      gload16(&kbase[(int64_t)(kv0 + rb + srow) * 1024 + sch8], &Ks[buf][rb * 64]);
      gload16(&vbase[(int64_t)(rb + srow) * TKV + kv0 + sch8], &Vs[buf][rb * 64]);
    }
  };

  STAGE(0, 0);
  __syncthreads();
  int cur = 0;
  for (int c = 0; c < 16; ++c) {
    int kv0 = c * 64;
    if (c < 15) STAGE(cur ^ 1, kv0 + 64);

    // mask prefetch (registers; resolves during QK^T)
    float mk[4][4];
#pragma unroll
    for (int nt = 0; nt < 4; nt++)
#pragma unroll
      for (int r = 0; r < 4; r++)
        mk[nt][r] = mbase[(int64_t)r * TKV + kv0 + nt * 16 + lr];

    int ch0 = (hi ^ sw) * 8, ch1 = ((hi + 4) ^ sw) * 8;
    f32x4 s[4];
#pragma unroll
    for (int nt = 0; nt < 4; nt++) {
      int row = (nt * 16 + lr) * 64;
      bf16x8 bk0 = *(const bf16x8*)&Ks[cur][row + ch0];
      bf16x8 bk1 = *(const bf16x8*)&Ks[cur][row + ch1];
      f32x4 z = (f32x4){0.f, 0.f, 0.f, 0.f};
      z = __builtin_amdgcn_mfma_f32_16x16x32_bf16(aq0, bk0, z, 0, 0, 0);
      z = __builtin_amdgcn_mfma_f32_16x16x32_bf16(aq1, bk1, z, 0, 0, 0);
      s[nt] = z;
    }
#pragma unroll
    for (int nt = 0; nt < 4; nt++)
#pragma unroll
      for (int r = 0; r < 4; r++) s[nt][r] += mk[nt][r];

    // online softmax (rows hi*4+r live across 16-lane lr-groups)
    float cm[4];
#pragma unroll
    for (int r = 0; r < 4; r++) {
      cm[r] = fmaxf(fmaxf(s[0][r], s[1][r]), fmaxf(s[2][r], s[3][r]));
#pragma unroll
      for (int d = 1; d < 16; d <<= 1) cm[r] = fmaxf(cm[r], __shfl_xor(cm[r], d));
    }
    float al[4], rs[4];
#pragma unroll
    for (int r = 0; r < 4; r++) {
      float nm = fmaxf(m[r], cm[r]);
      al[r] = __expf(m[r] - nm);
      m[r] = nm;
      rs[r] = 0.f;
    }
#pragma unroll
    for (int nt = 0; nt < 4; nt++)
#pragma unroll
      for (int r = 0; r < 4; r++) {
        s[nt][r] = __expf(s[nt][r] - m[r]);
        rs[r] += s[nt][r];
      }
#pragma unroll
    for (int r = 0; r < 4; r++) {
#pragma unroll
      for (int d = 1; d < 16; d <<= 1) rs[r] += __shfl_xor(rs[r], d);
      l[r] = l[r] * al[r] + rs[r];
    }
#pragma unroll
    for (int nt = 0; nt < 4; nt++)
#pragma unroll
      for (int r = 0; r < 4; r++) o[nt][r] *= al[r];

    // P -> bf16 via wave-private LDS (no barrier; compiler inserts lgkm waits)
#pragma unroll
    for (int nt = 0; nt < 4; nt++)
#pragma unroll
      for (int r = 0; r < 4; r++)
        Ps[w][(hi * 4 + r) * 76 + nt * 16 + lr] = f2bf(s[nt][r]);
    bf16x8 pa0 = *(const bf16x8*)&Ps[w][lr * 76 + hi * 8];
    bf16x8 pa1 = *(const bf16x8*)&Ps[w][lr * 76 + 32 + hi * 8];

#pragma unroll
    for (int nt = 0; nt < 4; nt++) {
      int row = (nt * 16 + lr) * 64;
      bf16x8 bv0 = *(const bf16x8*)&Vs[cur][row + ch0];
      bf16x8 bv1 = *(const bf16x8*)&Vs[cur][row + ch1];
      o[nt] = __builtin_amdgcn_mfma_f32_16x16x32_bf16(pa0, bv0, o[nt], 0, 0, 0);
      o[nt] = __builtin_amdgcn_mfma_f32_16x16x32_bf16(pa1, bv1, o[nt], 0, 0, 0);
    }
    __syncthreads();
    cur ^= 1;
  }

  float inv[4];
#pragma unroll
  for (int r = 0; r < 4; r++) inv[r] = 1.f / l[r];
#pragma unroll
  for (int nt = 0; nt < 4; nt++)
#pragma unroll
    for (int r = 0; r < 4; r++)
      wvb[(int64_t)(b * Tt + q0 + hi * 4 + r) * 1024 + h * DH + nt * 16 + lr] =
          f2bf(o[nt][r] * inv[r]);
}

// ---------------------------------------------------------------------------
extern "C" void kernel_launch(void* const* d_in, const int* in_sizes, int n_in,
                              void* d_out, int out_size, void* d_ws, size_t ws_size,
                              hipStream_t stream) {
  const float* x    = (const float*)d_in[0];
  const float* mask = (const float*)d_in[1];
  const float* ck   = (const float*)d_in[2];
  const float* cv   = (const float*)d_in[3];
  const float* Wq   = (const float*)d_in[4];
  const float* bq   = (const float*)d_in[5];
  const float* Wk   = (const float*)d_in[6];
  const float* Wv   = (const float*)d_in[7];
  const float* bv   = (const float*)d_in[8];
  const float* Wo   = (const float*)d_in[9];
  const float* bo   = (const float*)d_in[10];

  const int64_t NT = (int64_t)Bb * Tt * NS;   // 2097152
  float* outp = (float*)d_out;
  float* okf  = outp + NT;
  float* ovf  = outp + 2 * NT;

  char* ws = (char*)d_ws;
  unsigned short* xb  = (unsigned short*)(ws);                       // 4 MB
  unsigned short* wqt = (unsigned short*)(ws + (4LL << 20));         // 2 MB each
  unsigned short* wkt = (unsigned short*)(ws + (6LL << 20));
  unsigned short* wvt = (unsigned short*)(ws + (8LL << 20));
  unsigned short* wot = (unsigned short*)(ws + (10LL << 20));
  unsigned short* qbw = (unsigned short*)(ws + (12LL << 20));        // 4 MB
  unsigned short* kbw = (unsigned short*)(ws + (16LL << 20));        // 16 MB
  unsigned short* vbt = (unsigned short*)(ws + (32LL << 20));        // 16 MB
  unsigned short* wvb = (unsigned short*)(ws + (48LL << 20));        // 4 MB

  convert_flat<<<2048, 256, 0, stream>>>(x, ck, xb, kbw);
  transpose_convert<<<2560, 256, 0, stream>>>(Wq, Wk, Wv, Wo, cv, wqt, wkt, wvt, wot, vbt);
  gemm_mfma<0><<<768, 256, 0, stream>>>(xb, wqt, wkt, wvt, bq, bv, bo,
                                        qbw, okf, ovf, kbw, vbt, outp);
  attn<<<512, 256, 0, stream>>>(qbw, kbw, vbt, mask, wvb);
  gemm_mfma<1><<<512, 256, 0, stream>>>(wvb, wot, wot, wot, bq, bv, bo,
                                        qbw, okf, ovf, kbw, vbt, outp);
}